// Round 7
// baseline (48708.255 us; speedup 1.0000x reference)
//
#include <hip/hip_runtime.h>
#include <cstdint>
#include <cstddef>

// ---------------------------------------------------------------- sizes
#define LT 512
#define BB 128
#define DD 512
#define HH 1024
#define HD 1536
#define MT (LT*BB)   // 65536

typedef __bf16 bf16;
typedef __bf16 bf16x8 __attribute__((ext_vector_type(8)));
typedef __bf16 bf16x4 __attribute__((ext_vector_type(4)));
typedef float  f32x4  __attribute__((ext_vector_type(4)));

// ---------------------------------------------------------------- ws layout (bytes)
#define O_WZR 0u                 // bf16 [2048][1536]  rows 0..1023 = W_z, 1024.. = W_r
#define O_WHR 6291456u           // bf16 [1024][1024]  W_h[:, :H]
#define O_WXH 8388608u           // bf16 [1024][512]   W_h[:, H:]
#define O_XB  9437184u           // bf16 [65536][512]  x cast to bf16
#define O_HB  76546048u          // bf16 [128][1024]   h rounded (IF-coherent)
#define O_RHB 76808192u          // bf16 [128][1024]   r*h rounded (IF-coherent)
#define O_ZB  77070336u          // f32  [128][1024]   z gate (IF-coherent)
#define O_BAR 77594624u          // 8 groups x 1KB {slots[32], cntA@+160B/+192B, cntL@+256B/+384B}
#define WS_NEED 77602816u

#define WAIT_VM0() asm volatile("s_waitcnt vmcnt(0)" ::: "memory")
#define SCHED0()   __builtin_amdgcn_sched_barrier(0)

// ---------------------------------------------------------------- IF-coherent data access (R3-proven semantics)
__device__ __forceinline__ f32x4 ldc16(const void* p) {
  f32x4 r;
  asm volatile("global_load_dwordx4 %0, %1, off sc0 sc1" : "=&v"(r) : "v"(p) : "memory");
  return r;
}
__device__ __forceinline__ float ldc4(const void* p) {
  float r;
  asm volatile("global_load_dword %0, %1, off sc0 sc1" : "=&v"(r) : "v"(p) : "memory");
  return r;
}
__device__ __forceinline__ unsigned ldc2(const void* p) {
  unsigned r;
  asm volatile("global_load_ushort %0, %1, off sc0 sc1" : "=&v"(r) : "v"(p) : "memory");
  return r;
}
__device__ __forceinline__ void stc4(float* p, float v) {
  asm volatile("global_store_dword %0, %1, off sc0 sc1" :: "v"(p), "v"(v) : "memory");
}
__device__ __forceinline__ void stc2(bf16* p, unsigned v) {
  asm volatile("global_store_short %0, %1, off sc0 sc1" :: "v"(p), "v"(v) : "memory");
}
__device__ __forceinline__ unsigned bf16_bits(float f) {
  bf16 b = (bf16)f;
  return (unsigned)__builtin_bit_cast(unsigned short, b);
}
__device__ __forceinline__ float bits_to_f32(unsigned u16) {
  return __builtin_bit_cast(float, u16 << 16);
}

// ---------------------------------------------------------------- barrier
// Scope-oblivious monotonic barrier: every block posts arrival to BOTH a
// local word (WORKGROUP-scope RMW -> local L2 point) and an IF word
// (AGENT-scope RMW -> IF point, R3-proven). Polling prefers local (fast RMW
// poll, small guard), falls back to IF (which always has all arrivals).
// Atomic adds are conserved -> any cache-copy merge can only UNDERCOUNT ->
// never a false-early pass -> correct under ANY scope/mapping behavior.
// cntA is memset-zeroed per launch (agent-only word, no cached copies);
// cntL uses per-launch base captured in the post-step-0 quiescent window.
__device__ __forceinline__ void bar_sync(unsigned* cntL, unsigned* cntA,
                                         int t, unsigned baseL, int use_local) {
  WAIT_VM0();                       // my wave's coherent data stores are at IF
  __syncthreads();                  // all waves drained + arrived
  if (threadIdx.x == 0) {
    __hip_atomic_fetch_add(cntL, 1u, __ATOMIC_RELAXED, __HIP_MEMORY_SCOPE_WORKGROUP);
    __hip_atomic_fetch_add(cntA, 1u, __ATOMIC_RELAXED, __HIP_MEMORY_SCOPE_AGENT);
    if (t == 0) WAIT_VM0();         // step-0: adds at-point before pass => safe base capture
    int done = 0;
    if (use_local && t > 0) {
      unsigned tgtL = baseL + 32u*(unsigned)t;   // instances after capture = t
      int g = 400;
      while (__hip_atomic_fetch_add(cntL, 0u, __ATOMIC_RELAXED, __HIP_MEMORY_SCOPE_WORKGROUP) < tgtL
             && --g) __builtin_amdgcn_s_sleep(1);
      done = (g != 0);
    }
    if (!done) {
      unsigned tgtA = 32u*(unsigned)(t + 1);
      int g = 30000;
      while (__hip_atomic_load(cntA, __ATOMIC_RELAXED, __HIP_MEMORY_SCOPE_AGENT) < tgtA
             && --g) __builtin_amdgcn_s_sleep(2);
    }
  }
  __syncthreads();
}

// ---------------------------------------------------------------- small prep kernels
__global__ void k_cvt(const float* __restrict__ s, bf16* __restrict__ d, int n8) {
  int i = blockIdx.x*256 + threadIdx.x;
  if (i >= n8) return;
  const float4* p = (const float4*)s + (size_t)i*2;
  float4 a = p[0], b = p[1];
  bf16x8 v = {(bf16)a.x,(bf16)a.y,(bf16)a.z,(bf16)a.w,(bf16)b.x,(bf16)b.y,(bf16)b.z,(bf16)b.w};
  *((bf16x8*)d + i) = v;
}

__global__ void k_split_wh(const float* __restrict__ Wh, bf16* __restrict__ whr, bf16* __restrict__ wxh) {
  int i = blockIdx.x*256 + threadIdx.x;
  if (i >= 1024*192) return;
  int row = i / 192, c8 = (i % 192)*8;
  const float4* p = (const float4*)(Wh + (size_t)row*HD + c8);
  float4 a = p[0], b = p[1];
  bf16x8 v = {(bf16)a.x,(bf16)a.y,(bf16)a.z,(bf16)a.w,(bf16)b.x,(bf16)b.y,(bf16)b.z,(bf16)b.w};
  bf16* dptr = (c8 < HH) ? (whr + (size_t)row*HH + c8) : (wxh + (size_t)row*DD + (c8 - HH));
  *(bf16x8*)dptr = v;
}

__global__ void k_init_h(const float* __restrict__ h0, bf16* __restrict__ hb) {
  int i = blockIdx.x*256 + threadIdx.x;
  float4 a = ((const float4*)h0)[i];
  bf16x4 v = {(bf16)a.x,(bf16)a.y,(bf16)a.z,(bf16)a.w};
  *((bf16x4*)hb + i) = v;
}

// ---------------------------------------------------------------- Xh GEMM: out = x @ Wxh^T + b_h
__global__ __launch_bounds__(256) void k_gemm_xh(
    const bf16* __restrict__ xb, const bf16* __restrict__ wxh,
    const float* __restrict__ bh, float* __restrict__ out)
{
  __shared__ char As[16384];
  __shared__ char Bs[16384];
  const int bid = blockIdx.x;
  const int nt8 = bid & 7, mtb = bid >> 3;
  const int tid = threadIdx.x;
  const int lane = tid & 63, wv = tid >> 6;
  const int l15 = lane & 15, q = lane >> 4;
  const int wm = wv >> 1, wn = wv & 1;
  f32x4 acc[4][4] = {};
  const char* Ab = (const char*)(xb + (size_t)mtb*128*DD);
  const char* Bb = (const char*)(wxh + (size_t)nt8*128*DD);
  const int crow = tid >> 3, ccb = (tid & 7)*16;
  const int cdst = crow*128 + (ccb ^ ((crow & 7) << 4));
  for (int kt = 0; kt < 8; ++kt) {
    __syncthreads();
    #pragma unroll
    for (int i = 0; i < 4; ++i) {
      *(uint4*)(As + cdst + i*4096) = *(const uint4*)(Ab + (size_t)(crow + i*32)*1024 + kt*128 + ccb);
      *(uint4*)(Bs + cdst + i*4096) = *(const uint4*)(Bb + (size_t)(crow + i*32)*1024 + kt*128 + ccb);
    }
    __syncthreads();
    #pragma unroll
    for (int ks = 0; ks < 2; ++ks) {
      bf16x8 af[4], bfr[4];
      #pragma unroll
      for (int m4 = 0; m4 < 4; ++m4) {
        int row = wm*64 + m4*16 + l15, cb = ks*64 + 16*q;
        af[m4] = *(const bf16x8*)(As + row*128 + (cb ^ ((row&7)<<4)));
      }
      #pragma unroll
      for (int n4 = 0; n4 < 4; ++n4) {
        int row = wn*64 + n4*16 + l15, cb = ks*64 + 16*q;
        bfr[n4] = *(const bf16x8*)(Bs + row*128 + (cb ^ ((row&7)<<4)));
      }
      #pragma unroll
      for (int m4 = 0; m4 < 4; ++m4)
        #pragma unroll
        for (int n4 = 0; n4 < 4; ++n4)
          acc[m4][n4] = __builtin_amdgcn_mfma_f32_16x16x32_bf16(af[m4], bfr[n4], acc[m4][n4], 0, 0, 0);
    }
  }
  const int jb = nt8*128 + wn*64;
  const size_t mb = (size_t)mtb*128 + wm*64;
  #pragma unroll
  for (int n4 = 0; n4 < 4; ++n4) {
    int j = jb + n4*16 + l15;
    float bias = bh[j];
    #pragma unroll
    for (int m4 = 0; m4 < 4; ++m4)
      #pragma unroll
      for (int e = 0; e < 4; ++e) {
        size_t m = mb + m4*16 + 4*q + e;
        out[m*HH + j] = acc[m4][n4][e] + bias;
      }
  }
}

// ---------------------------------------------------------------- recurrent kernel
// 256 blocks x 512 threads; group g = bid&7 owns batch rows [g*16,+16)
// (groups proven XCD-uniform by R6's vote-pass). Data exchange: IF-coherent
// (R3-proven). Barriers: dual-point with local fast path (see bar_sync).
// sb = bid>>3 in [0,32): phase1 cols [sb*64,+64) of z|r (sb<16 -> z, else r);
// phase2 cols [sb*32,+32) of h_tilde. 8 waves: ch=wv&1 (col half), kh=wv>>1
// (K quarter); LDS reduce joins kh partials. Weights: 129KB LDS + 64 VGPR/thread.
struct Frags { bf16x8 zr[4][2]; bf16x8 h[8]; };

__global__ __launch_bounds__(512) void k_gru(
    const bf16* __restrict__ Wzr, const bf16* __restrict__ Whr,
    const bf16* __restrict__ xb, const float* __restrict__ h0,
    const float* __restrict__ bz, const float* __restrict__ br,
    float* __restrict__ out,
    bf16* __restrict__ hb, bf16* __restrict__ rhb, float* __restrict__ zbuf,
    unsigned* __restrict__ bar)
{
  extern __shared__ char smem[];
  char* ldsW = smem;            // W_zr LDS part: 64 cols x 2064B
  char* scr  = smem + 132096;   // 12KB kh-reduce scratch

  const int tid = threadIdx.x, bid = blockIdx.x;
  const int lane = tid & 63, wv = tid >> 6;
  const int l15 = lane & 15, q = lane >> 4;
  const int g = bid & 7, sb = bid >> 3;
  const int ch = wv & 1, kh = wv >> 1;
  unsigned* grp  = bar + g*256;   // words: slots[0..31]
  unsigned* cnt1A = grp + 40;     // agent-only (memset-fresh each launch)
  unsigned* cnt2A = grp + 48;
  unsigned* cnt1L = grp + 64;     // workgroup-RMW only (base-captured)
  unsigned* cnt2L = grp + 96;

  // stage LDS weights: cols [sb*64,+64), per-kh k-subrange [kh*384, kh*384+256)
  #pragma unroll
  for (int i = 0; i < 16; ++i) {
    int ci = tid + i*512;                  // 8192 chunks of 16B
    int row = ci >> 7, c = ci & 127;
    int le = c*8, khs = le >> 8, rem = le & 255;
    *(uint4*)(ldsW + row*2064 + c*16) =
      *(const uint4*)(Wzr + (size_t)(sb*64 + row)*HD + khs*384 + rem);
  }
  // VGPR weight fragments (per-wave quadrants)
  Frags F;
  #pragma unroll
  for (int i = 0; i < 4; ++i)
    #pragma unroll
    for (int nt = 0; nt < 2; ++nt)
      F.zr[i][nt] = *(const bf16x8*)(Wzr + (size_t)(sb*64 + ch*32 + nt*16 + l15)*HD
                                     + kh*384 + (8+i)*32 + 8*q);
  #pragma unroll
  for (int kk = 0; kk < 8; ++kk)
    F.h[kk] = *(const bf16x8*)(Whr + (size_t)(sb*32 + ch*16 + l15)*HH + kh*256 + kk*32 + 8*q);

  float bias[2];
  #pragma unroll
  for (int nt = 0; nt < 2; ++nt) {
    int c = sb*64 + ch*32 + nt*16 + l15;
    bias[nt] = (sb < 16) ? bz[c] : br[c - HH];
  }
  float hreg[4];
  const int jown = sb*32 + ch*16 + l15;
  #pragma unroll
  for (int e = 0; e < 4; ++e)
    hreg[e] = h0[(size_t)(g*16 + 4*q + e)*HH + jown];

  // ---- XCD vote (bounded; result tid0-only; perf-only — barriers are
  // correct either way since arrivals always go to both points).
  int use_local = 0;
  if (tid == 0) {
    int xcc;
    asm("s_getreg_b32 %0, hwreg(HW_REG_XCC_ID)" : "=s"(xcc));
    __hip_atomic_store(&grp[sb], (unsigned)(xcc + 1), __ATOMIC_RELAXED, __HIP_MEMORY_SCOPE_AGENT);
    unsigned first = 0; int ok = 1;
    long budget = 200000;
    for (int i = 0; i < 32; ++i) {
      unsigned v = 0;
      while (budget > 0) {
        v = __hip_atomic_load(&grp[i], __ATOMIC_RELAXED, __HIP_MEMORY_SCOPE_AGENT);
        if (v) break;
        --budget; __builtin_amdgcn_s_sleep(8);
      }
      if (!v) { ok = 0; break; }
      if (i == 0) first = v;
      else if (v != first) { ok = 0; break; }
    }
    use_local = ok;
  }
  __syncthreads();   // also covers LDS weight staging

  const bf16* hrow = hb  + (size_t)(g*16 + l15)*HH;
  const bf16* rrow = rhb + (size_t)(g*16 + l15)*HH;
  const int kh384 = kh*384, kh256 = kh*256;
  unsigned baseL1 = 0, baseL2 = 0;

  for (int t = 0; t < LT; ++t) {
    // ---------------- phase 1: z (sb<16) or r preacts, K=1536 ----------------
    {
      f32x4 ab[12];
      const bf16* xrow = xb + (size_t)(t*BB + g*16 + l15)*DD;
      #pragma unroll
      for (int kk = 0; kk < 12; ++kk) {
        int kabs = kh384 + kk*32;
        if (kabs < HH) ab[kk] = ldc16(hrow + kabs + 8*q);                  // coherent
        else           ab[kk] = *(const f32x4*)(xrow + (kabs - HH) + 8*q); // plain cached
      }
      unsigned hv[2][4];
      if (sb >= 16 && kh == 0) {           // r-block: prefetch cross-block h
        #pragma unroll
        for (int nt = 0; nt < 2; ++nt) {
          int cr = sb*64 - HH + ch*32 + nt*16 + l15;
          #pragma unroll
          for (int e = 0; e < 4; ++e)
            hv[nt][e] = ldc2(hb + (size_t)(g*16 + 4*q + e)*HH + cr);
        }
      }
      WAIT_VM0(); SCHED0();
      f32x4 a0 = {}, a1 = {};
      #pragma unroll
      for (int kk = 0; kk < 12; ++kk) {
        bf16x8 a = __builtin_bit_cast(bf16x8, ab[kk]);
        bf16x8 b0, b1;
        if (kk < 8) {
          b0 = *(const bf16x8*)(ldsW + (ch*32      + l15)*2064 + kh*512 + kk*64 + 16*q);
          b1 = *(const bf16x8*)(ldsW + (ch*32 + 16 + l15)*2064 + kh*512 + kk*64 + 16*q);
        } else { b0 = F.zr[kk-8][0]; b1 = F.zr[kk-8][1]; }
        a0 = __builtin_amdgcn_mfma_f32_16x16x32_bf16(a, b0, a0, 0, 0, 0);
        a1 = __builtin_amdgcn_mfma_f32_16x16x32_bf16(a, b1, a1, 0, 0, 0);
      }
      if (kh) {
        int s = ((kh-1)*2 + ch)*2;
        *(f32x4*)(scr + (s+0)*1024 + lane*16) = a0;
        *(f32x4*)(scr + (s+1)*1024 + lane*16) = a1;
      }
      __syncthreads();
      if (kh == 0) {
        #pragma unroll
        for (int k2 = 0; k2 < 3; ++k2) {
          int s = (k2*2 + ch)*2;
          a0 += *(const f32x4*)(scr + (s+0)*1024 + lane*16);
          a1 += *(const f32x4*)(scr + (s+1)*1024 + lane*16);
        }
        if (sb < 16) {                       // ---- z block ----
          #pragma unroll
          for (int nt = 0; nt < 2; ++nt) {
            f32x4 ac = nt ? a1 : a0;
            int c = sb*64 + ch*32 + nt*16 + l15;
            #pragma unroll
            for (int e = 0; e < 4; ++e) {
              int m = g*16 + 4*q + e;
              float gate = 1.f/(1.f + __expf(-(ac[e] + bias[nt])));
              stc4(zbuf + (size_t)m*HH + c, gate);
            }
          }
        } else {                             // ---- r block ----
          #pragma unroll
          for (int nt = 0; nt < 2; ++nt) {
            f32x4 ac = nt ? a1 : a0;
            int cr = sb*64 - HH + ch*32 + nt*16 + l15;
            #pragma unroll
            for (int e = 0; e < 4; ++e) {
              int m = g*16 + 4*q + e;
              float gate = 1.f/(1.f + __expf(-(ac[e] + bias[nt])));
              stc2(rhb + (size_t)m*HH + cr, bf16_bits(gate * bits_to_f32(hv[nt][e])));
            }
          }
        }
      }
    }
    bar_sync(cnt1L, cnt1A, t, baseL1, use_local);
    // ---------------- phase 2: h_tilde + combine, K=1024 ----------------
    {
      f32x4 rb[8];
      #pragma unroll
      for (int kk = 0; kk < 8; ++kk)
        rb[kk] = ldc16(rrow + kh256 + kk*32 + 8*q);
      float zv[4], xh[4];
      if (kh == 0) {
        #pragma unroll
        for (int e = 0; e < 4; ++e) {
          int m = g*16 + 4*q + e;
          zv[e] = ldc4(zbuf + (size_t)m*HH + jown);                        // coherent
          xh[e] = out[(size_t)t*(BB*HH) + (size_t)m*HH + jown];            // plain: Xh+b_h
        }
      }
      WAIT_VM0(); SCHED0();
      f32x4 acc = {};
      #pragma unroll
      for (int kk = 0; kk < 8; ++kk)
        acc = __builtin_amdgcn_mfma_f32_16x16x32_bf16(
            __builtin_bit_cast(bf16x8, rb[kk]), F.h[kk], acc, 0, 0, 0);
      if (kh) *(f32x4*)(scr + ((kh-1)*2 + ch)*1024 + lane*16) = acc;
      __syncthreads();
      if (kh == 0) {
        #pragma unroll
        for (int k2 = 0; k2 < 3; ++k2)
          acc += *(const f32x4*)(scr + (k2*2 + ch)*1024 + lane*16);
        #pragma unroll
        for (int e = 0; e < 4; ++e) {
          int m = g*16 + 4*q + e;
          size_t idx = (size_t)m*HH + jown;
          size_t oidx = (size_t)t*(BB*HH) + idx;
          float ht = tanhf(acc[e] + xh[e]);
          float hn = hreg[e] + zv[e]*(ht - hreg[e]);
          out[oidx] = hn;                    // plain store (block-private slot)
          hreg[e] = hn;
          stc2(hb + idx, bf16_bits(hn));     // next step's h
        }
      }
    }
    bar_sync(cnt2L, cnt2A, t, baseL2, use_local);
    // quiescent window (next local adds are >= one full phase away):
    // capture per-launch local-counter bases once, after step-0 barriers.
    if (t == 0 && tid == 0) {
      baseL1 = __hip_atomic_fetch_add(cnt1L, 0u, __ATOMIC_RELAXED, __HIP_MEMORY_SCOPE_WORKGROUP);
      baseL2 = __hip_atomic_fetch_add(cnt2L, 0u, __ATOMIC_RELAXED, __HIP_MEMORY_SCOPE_WORKGROUP);
    }
  }
}

// ---------------------------------------------------------------- launch
extern "C" void kernel_launch(void* const* d_in, const int* in_sizes, int n_in,
                              void* d_out, int out_size, void* d_ws, size_t ws_size,
                              hipStream_t stream) {
  const float* x  = (const float*)d_in[0];
  const float* h0 = (const float*)d_in[1];
  const float* Wz = (const float*)d_in[2];
  const float* bz = (const float*)d_in[3];
  const float* Wr = (const float*)d_in[4];
  const float* br = (const float*)d_in[5];
  const float* Wh = (const float*)d_in[6];
  const float* bh = (const float*)d_in[7];
  float* out = (float*)d_out;
  char* ws = (char*)d_ws;
  if (ws_size < (size_t)WS_NEED) return;

  bf16*  wzr  = (bf16*) (ws + O_WZR);
  bf16*  whr  = (bf16*) (ws + O_WHR);
  bf16*  wxh  = (bf16*) (ws + O_WXH);
  bf16*  xbb  = (bf16*) (ws + O_XB);
  bf16*  hb   = (bf16*) (ws + O_HB);
  bf16*  rhb  = (bf16*) (ws + O_RHB);
  float* zbuf = (float*)(ws + O_ZB);
  unsigned* bar = (unsigned*)(ws + O_BAR);

  hipMemsetAsync(bar, 0, 8192, stream);   // vote slots + IF counters (agent-only words)
  k_cvt<<<16384, 256, 0, stream>>>(x, xbb, MT*DD/8);
  k_cvt<<<768, 256, 0, stream>>>(Wz, wzr, HH*HD/8);
  k_cvt<<<768, 256, 0, stream>>>(Wr, wzr + (size_t)HH*HD, HH*HD/8);
  k_split_wh<<<768, 256, 0, stream>>>(Wh, whr, wxh);
  k_init_h<<<128, 256, 0, stream>>>(h0, hb);
  k_gemm_xh<<<4096, 256, 0, stream>>>(xbb, wxh, bh, out);

  hipFuncSetAttribute((const void*)k_gru, hipFuncAttributeMaxDynamicSharedMemorySize, 144384);
  k_gru<<<256, 512, 144384, stream>>>(wzr, whr, xbb, h0, bz, br, out, hb, rhb, zbuf, bar);
}

// Round 8
// 6443.438 us; speedup vs baseline: 7.5594x; 7.5594x over previous
//
#include <hip/hip_runtime.h>
#include <cstdint>
#include <cstddef>

// ---------------------------------------------------------------- sizes
#define LT 512
#define BB 128
#define DD 512
#define HH 1024
#define HD 1536
#define MT (LT*BB)   // 65536

typedef __bf16 bf16;
typedef __bf16 bf16x8 __attribute__((ext_vector_type(8)));
typedef __bf16 bf16x4 __attribute__((ext_vector_type(4)));
typedef float  f32x4  __attribute__((ext_vector_type(4)));

// ---------------------------------------------------------------- ws layout (bytes)
#define O_WZR 0u                 // bf16 [2048][1536]  rows 0..1023 = W_z, 1024.. = W_r
#define O_WHR 6291456u           // bf16 [1024][1024]  W_h[:, :H]
#define O_WXH 8388608u           // bf16 [1024][512]   W_h[:, H:]
#define O_XB  9437184u           // bf16 [65536][512]  x cast to bf16
#define O_HB  76546048u          // bf16 [128][1024]   h rounded (IF-coherent)
#define O_RHB 76808192u          // bf16 [128][1024]   r*h rounded (IF-coherent)
#define O_ZB  77070336u          // f32  [128][1024]   z gate (IF-coherent)
#define O_BAR 77594624u          // 8 groups x 8KB {slots[32], cntA x2, local cnt[2][512]}
#define WS_NEED 77660160u

#define WAIT_VM0() asm volatile("s_waitcnt vmcnt(0)" ::: "memory")
#define SCHED0()   __builtin_amdgcn_sched_barrier(0)

// ---------------------------------------------------------------- IF-coherent data access (R3-proven semantics)
__device__ __forceinline__ f32x4 ldc16(const void* p) {
  f32x4 r;
  asm volatile("global_load_dwordx4 %0, %1, off sc0 sc1" : "=&v"(r) : "v"(p) : "memory");
  return r;
}
__device__ __forceinline__ float ldc4(const void* p) {
  float r;
  asm volatile("global_load_dword %0, %1, off sc0 sc1" : "=&v"(r) : "v"(p) : "memory");
  return r;
}
__device__ __forceinline__ unsigned ldc2(const void* p) {
  unsigned r;
  asm volatile("global_load_ushort %0, %1, off sc0 sc1" : "=&v"(r) : "v"(p) : "memory");
  return r;
}
__device__ __forceinline__ void stc4(float* p, float v) {
  asm volatile("global_store_dword %0, %1, off sc0 sc1" :: "v"(p), "v"(v) : "memory");
}
__device__ __forceinline__ void stc2(bf16* p, unsigned v) {
  asm volatile("global_store_short %0, %1, off sc0 sc1" :: "v"(p), "v"(v) : "memory");
}
__device__ __forceinline__ unsigned bf16_bits(float f) {
  bf16 b = (bf16)f;
  return (unsigned)__builtin_bit_cast(unsigned short, b);
}
__device__ __forceinline__ float bits_to_f32(unsigned u16) {
  return __builtin_bit_cast(float, u16 << 16);
}

// ---------------------------------------------------------------- local-point atomics (no sc1 -> nearest atomic point)
// Arrival and poll are the SAME atomic class -> they meet at the same cache
// point regardless of where gfx950 executes no-sc1 atomics => convergence is
// semantics-proof; only latency depends on the point (local L2 expected).
// Poll is a returning HW RMW (asm volatile): immune to both the idempotent
// atomicrmw->load optimization AND L1 staleness (atomics never hit L1).
__device__ __forceinline__ void loc_add(unsigned* p) {
  asm volatile("global_atomic_add %0, %1, off" :: "v"(p), "v"(1u) : "memory");
}
__device__ __forceinline__ unsigned loc_rmw0(unsigned* p) {
  unsigned old;
  asm volatile("global_atomic_add %0, %1, %2, off sc0\n\ts_waitcnt vmcnt(0)"
               : "=&v"(old) : "v"(p), "v"(0u) : "memory");
  return old;
}
__device__ __forceinline__ void loc_clr(unsigned* p) {
  asm volatile("global_atomic_and %0, %1, off" :: "v"(p), "v"(0u) : "memory");
}

// ---------------------------------------------------------------- barrier
// Dual arrival: IF counter (agent builtin, R3-proven) + per-step local word.
// Poll: t<2 -> IF (proven; covers replay-stale local lines before first
// in-launch clear). t>=2 -> local RMW-poll vs 32 (per-step word, cleared by
// block 0 at step t-2 -> no reset races, no base capture). Guarded; on
// exhaustion demote permanently to IF polling (bounded worst case, no 600s
// timeout, correctness preserved since IF counter has all arrivals).
__device__ __forceinline__ void bar_sync(unsigned* cntA, unsigned* cntLt,
                                         int t, int voteok, int& use_local,
                                         unsigned tgtA) {
  WAIT_VM0();                       // my wave's coherent data stores are at IF
  __syncthreads();                  // all waves drained + arrived
  if (threadIdx.x == 0) {
    __hip_atomic_fetch_add(cntA, 1u, __ATOMIC_RELAXED, __HIP_MEMORY_SCOPE_AGENT);
    if (voteok) loc_add(cntLt);
    int done = 0;
    if (use_local && t >= 2) {
      int gd = 20000;
      while (gd--) {
        if (loc_rmw0(cntLt) >= 32u) { done = 1; break; }
        __builtin_amdgcn_s_sleep(2);
      }
      if (!done) use_local = 0;     // demote: local point never converged
    }
    if (!done) {
      int gd = 60000;
      while (__hip_atomic_load(cntA, __ATOMIC_RELAXED, __HIP_MEMORY_SCOPE_AGENT) < tgtA
             && --gd) __builtin_amdgcn_s_sleep(2);
    }
  }
  __syncthreads();
}

// ---------------------------------------------------------------- small prep kernels
__global__ void k_cvt(const float* __restrict__ s, bf16* __restrict__ d, int n8) {
  int i = blockIdx.x*256 + threadIdx.x;
  if (i >= n8) return;
  const float4* p = (const float4*)s + (size_t)i*2;
  float4 a = p[0], b = p[1];
  bf16x8 v = {(bf16)a.x,(bf16)a.y,(bf16)a.z,(bf16)a.w,(bf16)b.x,(bf16)b.y,(bf16)b.z,(bf16)b.w};
  *((bf16x8*)d + i) = v;
}

__global__ void k_split_wh(const float* __restrict__ Wh, bf16* __restrict__ whr, bf16* __restrict__ wxh) {
  int i = blockIdx.x*256 + threadIdx.x;
  if (i >= 1024*192) return;
  int row = i / 192, c8 = (i % 192)*8;
  const float4* p = (const float4*)(Wh + (size_t)row*HD + c8);
  float4 a = p[0], b = p[1];
  bf16x8 v = {(bf16)a.x,(bf16)a.y,(bf16)a.z,(bf16)a.w,(bf16)b.x,(bf16)b.y,(bf16)b.z,(bf16)b.w};
  bf16* dptr = (c8 < HH) ? (whr + (size_t)row*HH + c8) : (wxh + (size_t)row*DD + (c8 - HH));
  *(bf16x8*)dptr = v;
}

__global__ void k_init_h(const float* __restrict__ h0, bf16* __restrict__ hb) {
  int i = blockIdx.x*256 + threadIdx.x;
  float4 a = ((const float4*)h0)[i];
  bf16x4 v = {(bf16)a.x,(bf16)a.y,(bf16)a.z,(bf16)a.w};
  *((bf16x4*)hb + i) = v;
}

// ---------------------------------------------------------------- Xh GEMM: out = x @ Wxh^T + b_h
__global__ __launch_bounds__(256) void k_gemm_xh(
    const bf16* __restrict__ xb, const bf16* __restrict__ wxh,
    const float* __restrict__ bh, float* __restrict__ out)
{
  __shared__ char As[16384];
  __shared__ char Bs[16384];
  const int bid = blockIdx.x;
  const int nt8 = bid & 7, mtb = bid >> 3;
  const int tid = threadIdx.x;
  const int lane = tid & 63, wv = tid >> 6;
  const int l15 = lane & 15, q = lane >> 4;
  const int wm = wv >> 1, wn = wv & 1;
  f32x4 acc[4][4] = {};
  const char* Ab = (const char*)(xb + (size_t)mtb*128*DD);
  const char* Bb = (const char*)(wxh + (size_t)nt8*128*DD);
  const int crow = tid >> 3, ccb = (tid & 7)*16;
  const int cdst = crow*128 + (ccb ^ ((crow & 7) << 4));
  for (int kt = 0; kt < 8; ++kt) {
    __syncthreads();
    #pragma unroll
    for (int i = 0; i < 4; ++i) {
      *(uint4*)(As + cdst + i*4096) = *(const uint4*)(Ab + (size_t)(crow + i*32)*1024 + kt*128 + ccb);
      *(uint4*)(Bs + cdst + i*4096) = *(const uint4*)(Bb + (size_t)(crow + i*32)*1024 + kt*128 + ccb);
    }
    __syncthreads();
    #pragma unroll
    for (int ks = 0; ks < 2; ++ks) {
      bf16x8 af[4], bfr[4];
      #pragma unroll
      for (int m4 = 0; m4 < 4; ++m4) {
        int row = wm*64 + m4*16 + l15, cb = ks*64 + 16*q;
        af[m4] = *(const bf16x8*)(As + row*128 + (cb ^ ((row&7)<<4)));
      }
      #pragma unroll
      for (int n4 = 0; n4 < 4; ++n4) {
        int row = wn*64 + n4*16 + l15, cb = ks*64 + 16*q;
        bfr[n4] = *(const bf16x8*)(Bs + row*128 + (cb ^ ((row&7)<<4)));
      }
      #pragma unroll
      for (int m4 = 0; m4 < 4; ++m4)
        #pragma unroll
        for (int n4 = 0; n4 < 4; ++n4)
          acc[m4][n4] = __builtin_amdgcn_mfma_f32_16x16x32_bf16(af[m4], bfr[n4], acc[m4][n4], 0, 0, 0);
    }
  }
  const int jb = nt8*128 + wn*64;
  const size_t mb = (size_t)mtb*128 + wm*64;
  #pragma unroll
  for (int n4 = 0; n4 < 4; ++n4) {
    int j = jb + n4*16 + l15;
    float bias = bh[j];
    #pragma unroll
    for (int m4 = 0; m4 < 4; ++m4)
      #pragma unroll
      for (int e = 0; e < 4; ++e) {
        size_t m = mb + m4*16 + 4*q + e;
        out[m*HH + j] = acc[m4][n4][e] + bias;
      }
  }
}

// ---------------------------------------------------------------- recurrent kernel
// 256 blocks x 512 threads; group g = bid&7 owns batch rows [g*16,+16)
// (groups XCD-uniform: confirmed by R6's vote-pass). Data exchange IF-coherent
// (R3-proven). Barriers: local-L2 RMW with IF fallback (see bar_sync).
// sb = bid>>3 in [0,32): phase1 cols [sb*64,+64) of z|r (sb<16 -> z, else r);
// phase2 cols [sb*32,+32) of h_tilde. 8 waves: ch=wv&1 (col half), kh=wv>>1
// (K quarter); LDS reduce joins kh partials. Weights: 129KB LDS + 64 VGPR/thread.
struct Frags { bf16x8 zr[4][2]; bf16x8 h[8]; };

__global__ __launch_bounds__(512) void k_gru(
    const bf16* __restrict__ Wzr, const bf16* __restrict__ Whr,
    const bf16* __restrict__ xb, const float* __restrict__ h0,
    const float* __restrict__ bz, const float* __restrict__ br,
    float* __restrict__ out,
    bf16* __restrict__ hb, bf16* __restrict__ rhb, float* __restrict__ zbuf,
    unsigned* __restrict__ bar)
{
  extern __shared__ char smem[];
  char* ldsW = smem;            // W_zr LDS part: 64 cols x 2064B
  char* scr  = smem + 132096;   // 12KB kh-reduce scratch

  const int tid = threadIdx.x, bid = blockIdx.x;
  const int lane = tid & 63, wv = tid >> 6;
  const int l15 = lane & 15, q = lane >> 4;
  const int g = bid & 7, sb = bid >> 3;
  const int ch = wv & 1, kh = wv >> 1;
  unsigned* grp   = bar + (size_t)g*2048;  // 8KB/group (word units)
  unsigned* cnt1A = grp + 40;              // IF counters (memset-fresh)
  unsigned* cnt2A = grp + 48;
  unsigned* cnt1L = grp + 256;             // local per-step words [512]
  unsigned* cnt2L = grp + 1024;            // local per-step words [512]

  // stage LDS weights: cols [sb*64,+64), per-kh k-subrange [kh*384, kh*384+256)
  #pragma unroll
  for (int i = 0; i < 16; ++i) {
    int ci = tid + i*512;                  // 8192 chunks of 16B
    int row = ci >> 7, c = ci & 127;
    int le = c*8, khs = le >> 8, rem = le & 255;
    *(uint4*)(ldsW + row*2064 + c*16) =
      *(const uint4*)(Wzr + (size_t)(sb*64 + row)*HD + khs*384 + rem);
  }
  // VGPR weight fragments (per-wave quadrants)
  Frags F;
  #pragma unroll
  for (int i = 0; i < 4; ++i)
    #pragma unroll
    for (int nt = 0; nt < 2; ++nt)
      F.zr[i][nt] = *(const bf16x8*)(Wzr + (size_t)(sb*64 + ch*32 + nt*16 + l15)*HD
                                     + kh*384 + (8+i)*32 + 8*q);
  #pragma unroll
  for (int kk = 0; kk < 8; ++kk)
    F.h[kk] = *(const bf16x8*)(Whr + (size_t)(sb*32 + ch*16 + l15)*HH + kh*256 + kk*32 + 8*q);

  float bias[2];
  #pragma unroll
  for (int nt = 0; nt < 2; ++nt) {
    int c = sb*64 + ch*32 + nt*16 + l15;
    bias[nt] = (sb < 16) ? bz[c] : br[c - HH];
  }
  float hreg[4];
  const int jown = sb*32 + ch*16 + l15;
  #pragma unroll
  for (int e = 0; e < 4; ++e)
    hreg[e] = h0[(size_t)(g*16 + 4*q + e)*HH + jown];

  // ---- XCD vote (bounded; tid0-only result; perf-only — fallback correct).
  int voteok = 0;
  if (tid == 0) {
    int xcc;
    asm("s_getreg_b32 %0, hwreg(HW_REG_XCC_ID)" : "=s"(xcc));
    __hip_atomic_store(&grp[sb], (unsigned)(xcc + 1), __ATOMIC_RELAXED, __HIP_MEMORY_SCOPE_AGENT);
    unsigned first = 0; int ok = 1;
    long budget = 200000;
    for (int i = 0; i < 32; ++i) {
      unsigned v = 0;
      while (budget > 0) {
        v = __hip_atomic_load(&grp[i], __ATOMIC_RELAXED, __HIP_MEMORY_SCOPE_AGENT);
        if (v) break;
        --budget; __builtin_amdgcn_s_sleep(8);
      }
      if (!v) { ok = 0; break; }
      if (i == 0) first = v;
      else if (v != first) { ok = 0; break; }
    }
    voteok = ok;
  }
  __syncthreads();   // also covers LDS weight staging
  int use_local = voteok;            // mutable (demotion), tid0-only meaningful
  const int do_clr = (sb == 0);      // block 0 of the group clears t+2 words

  const bf16* hrow = hb  + (size_t)(g*16 + l15)*HH;
  const bf16* rrow = rhb + (size_t)(g*16 + l15)*HH;
  const int kh384 = kh*384, kh256 = kh*256;

  for (int t = 0; t < LT; ++t) {
    // ---------------- phase 1: z (sb<16) or r preacts, K=1536 ----------------
    {
      f32x4 ab[12];
      const bf16* xrow = xb + (size_t)(t*BB + g*16 + l15)*DD;
      #pragma unroll
      for (int kk = 0; kk < 12; ++kk) {
        int kabs = kh384 + kk*32;
        if (kabs < HH) ab[kk] = ldc16(hrow + kabs + 8*q);                  // coherent
        else           ab[kk] = *(const f32x4*)(xrow + (kabs - HH) + 8*q); // plain cached
      }
      unsigned hv[2][4];
      if (sb >= 16 && kh == 0) {           // r-block: prefetch cross-block h
        #pragma unroll
        for (int nt = 0; nt < 2; ++nt) {
          int cr = sb*64 - HH + ch*32 + nt*16 + l15;
          #pragma unroll
          for (int e = 0; e < 4; ++e)
            hv[nt][e] = ldc2(hb + (size_t)(g*16 + 4*q + e)*HH + cr);
        }
      }
      WAIT_VM0(); SCHED0();
      f32x4 a0 = {}, a1 = {};
      #pragma unroll
      for (int kk = 0; kk < 12; ++kk) {
        bf16x8 a = __builtin_bit_cast(bf16x8, ab[kk]);
        bf16x8 b0, b1;
        if (kk < 8) {
          b0 = *(const bf16x8*)(ldsW + (ch*32      + l15)*2064 + kh*512 + kk*64 + 16*q);
          b1 = *(const bf16x8*)(ldsW + (ch*32 + 16 + l15)*2064 + kh*512 + kk*64 + 16*q);
        } else { b0 = F.zr[kk-8][0]; b1 = F.zr[kk-8][1]; }
        a0 = __builtin_amdgcn_mfma_f32_16x16x32_bf16(a, b0, a0, 0, 0, 0);
        a1 = __builtin_amdgcn_mfma_f32_16x16x32_bf16(a, b1, a1, 0, 0, 0);
      }
      if (kh) {
        int s = ((kh-1)*2 + ch)*2;
        *(f32x4*)(scr + (s+0)*1024 + lane*16) = a0;
        *(f32x4*)(scr + (s+1)*1024 + lane*16) = a1;
      }
      __syncthreads();
      if (kh == 0) {
        #pragma unroll
        for (int k2 = 0; k2 < 3; ++k2) {
          int s = (k2*2 + ch)*2;
          a0 += *(const f32x4*)(scr + (s+0)*1024 + lane*16);
          a1 += *(const f32x4*)(scr + (s+1)*1024 + lane*16);
        }
        if (sb < 16) {                       // ---- z block ----
          #pragma unroll
          for (int nt = 0; nt < 2; ++nt) {
            f32x4 ac = nt ? a1 : a0;
            int c = sb*64 + ch*32 + nt*16 + l15;
            #pragma unroll
            for (int e = 0; e < 4; ++e) {
              int m = g*16 + 4*q + e;
              float gate = 1.f/(1.f + __expf(-(ac[e] + bias[nt])));
              stc4(zbuf + (size_t)m*HH + c, gate);
            }
          }
        } else {                             // ---- r block ----
          #pragma unroll
          for (int nt = 0; nt < 2; ++nt) {
            f32x4 ac = nt ? a1 : a0;
            int cr = sb*64 - HH + ch*32 + nt*16 + l15;
            #pragma unroll
            for (int e = 0; e < 4; ++e) {
              int m = g*16 + 4*q + e;
              float gate = 1.f/(1.f + __expf(-(ac[e] + bias[nt])));
              stc2(rhb + (size_t)m*HH + cr, bf16_bits(gate * bits_to_f32(hv[nt][e])));
            }
          }
        }
      }
    }
    bar_sync(cnt1A, cnt1L + t, t, voteok, use_local, 32u*(unsigned)(t+1));
    // ---------------- phase 2: h_tilde + combine, K=1024 ----------------
    {
      f32x4 rb[8];
      #pragma unroll
      for (int kk = 0; kk < 8; ++kk)
        rb[kk] = ldc16(rrow + kh256 + kk*32 + 8*q);
      float zv[4], xh[4];
      if (kh == 0) {
        #pragma unroll
        for (int e = 0; e < 4; ++e) {
          int m = g*16 + 4*q + e;
          zv[e] = ldc4(zbuf + (size_t)m*HH + jown);                        // coherent
          xh[e] = out[(size_t)t*(BB*HH) + (size_t)m*HH + jown];            // plain: Xh+b_h
        }
      }
      WAIT_VM0(); SCHED0();
      f32x4 acc = {};
      #pragma unroll
      for (int kk = 0; kk < 8; ++kk)
        acc = __builtin_amdgcn_mfma_f32_16x16x32_bf16(
            __builtin_bit_cast(bf16x8, rb[kk]), F.h[kk], acc, 0, 0, 0);
      if (kh) *(f32x4*)(scr + ((kh-1)*2 + ch)*1024 + lane*16) = acc;
      __syncthreads();
      if (kh == 0) {
        #pragma unroll
        for (int k2 = 0; k2 < 3; ++k2)
          acc += *(const f32x4*)(scr + (k2*2 + ch)*1024 + lane*16);
        #pragma unroll
        for (int e = 0; e < 4; ++e) {
          int m = g*16 + 4*q + e;
          size_t idx = (size_t)m*HH + jown;
          size_t oidx = (size_t)t*(BB*HH) + idx;
          float ht = tanhf(acc[e] + xh[e]);
          float hn = hreg[e] + zv[e]*(ht - hreg[e]);
          out[oidx] = hn;                    // plain store (block-private slot)
          hreg[e] = hn;
          stc2(hb + idx, bf16_bits(hn));     // next step's h
        }
      }
    }
    bar_sync(cnt2A, cnt2L + t, t, voteok, use_local, 32u*(unsigned)(t+1));
    // In-launch clear of step t+2's local counters by block 0 (tid0). Ordered:
    // clear -> (vmcnt drain at next bar entry) -> block0's t+1 arrivals ->
    // everyone's t+1 release -> earliest possible t+2 arrival. No race.
    if (tid == 0 && do_clr && voteok && t + 2 < LT) {
      loc_clr(cnt1L + t + 2);
      loc_clr(cnt2L + t + 2);
    }
  }
}

// ---------------------------------------------------------------- launch
extern "C" void kernel_launch(void* const* d_in, const int* in_sizes, int n_in,
                              void* d_out, int out_size, void* d_ws, size_t ws_size,
                              hipStream_t stream) {
  const float* x  = (const float*)d_in[0];
  const float* h0 = (const float*)d_in[1];
  const float* Wz = (const float*)d_in[2];
  const float* bz = (const float*)d_in[3];
  const float* Wr = (const float*)d_in[4];
  const float* br = (const float*)d_in[5];
  const float* Wh = (const float*)d_in[6];
  const float* bh = (const float*)d_in[7];
  float* out = (float*)d_out;
  char* ws = (char*)d_ws;
  if (ws_size < (size_t)WS_NEED) return;

  bf16*  wzr  = (bf16*) (ws + O_WZR);
  bf16*  whr  = (bf16*) (ws + O_WHR);
  bf16*  wxh  = (bf16*) (ws + O_WXH);
  bf16*  xbb  = (bf16*) (ws + O_XB);
  bf16*  hb   = (bf16*) (ws + O_HB);
  bf16*  rhb  = (bf16*) (ws + O_RHB);
  float* zbuf = (float*)(ws + O_ZB);
  unsigned* bar = (unsigned*)(ws + O_BAR);

  hipMemsetAsync(bar, 0, 65536, stream);  // vote slots + IF counters (+ local words at IF)
  k_cvt<<<16384, 256, 0, stream>>>(x, xbb, MT*DD/8);
  k_cvt<<<768, 256, 0, stream>>>(Wz, wzr, HH*HD/8);
  k_cvt<<<768, 256, 0, stream>>>(Wr, wzr + (size_t)HH*HD, HH*HD/8);
  k_split_wh<<<768, 256, 0, stream>>>(Wh, whr, wxh);
  k_init_h<<<128, 256, 0, stream>>>(h0, hb);
  k_gemm_xh<<<4096, 256, 0, stream>>>(xbb, wxh, bh, out);

  hipFuncSetAttribute((const void*)k_gru, hipFuncAttributeMaxDynamicSharedMemorySize, 144384);
  k_gru<<<256, 512, 144384, stream>>>(wzr, whr, xbb, h0, bz, br, out, hb, rhb, zbuf, bar);
}